// Round 8
// baseline (325.983 us; speedup 1.0000x reference)
//
#include <hip/hip_runtime.h>

// MultiHeadSelfAttention: x[4,2048,1024], w_qkv[3072,1024], w_o[1024,1024]
// Inputs fp32 (runtime-detected); all compute bf16 MFMA; every intermediate
// stored FRAGMENT-READY so every MFMA operand load is base + lane*16B.
#define BATCH 4
#define SEQ 2048
#define DM 1024
#define NH 16
#define DH 64
#define M_TOT (BATCH * SEQ)   // 8192
#define EQKV (3 * DM)         // 3072
// 0.125 (1/sqrt(dh)) * log2(e): folded into Q; softmax in exp2 domain
#define QSCALE 0.18033688011112042f

typedef __bf16 bf16x8 __attribute__((ext_vector_type(8)));
typedef unsigned short u16x8 __attribute__((ext_vector_type(8)));
typedef float f32x4 __attribute__((ext_vector_type(4)));
typedef float f32x16 __attribute__((ext_vector_type(16)));

// RNE fp32->bf16 (used only in input canonicalization)
static __device__ __forceinline__ unsigned short f2bf(float f) {
    unsigned int u = __builtin_bit_cast(unsigned int, f);
    u += 0x7fffu + ((u >> 16) & 1u);
    return (unsigned short)(u >> 16);
}

// fast fp32->bf16, round-half-up (2 VALU): bias +2^-17 relative, negligible
static __device__ __forceinline__ unsigned short f2bf_fast(float f) {
    return (unsigned short)((__builtin_bit_cast(unsigned int, f) + 0x8000u) >> 16);
}

// fast pack two fp32 -> bf16 pair (3 VALU: 2 adds + 1 v_perm_b32)
static __device__ __forceinline__ unsigned int pkbf_fast(float a, float b) {
    unsigned int ua = __builtin_bit_cast(unsigned int, a) + 0x8000u;
    unsigned int ub = __builtin_bit_cast(unsigned int, b) + 0x8000u;
#if __has_builtin(__builtin_amdgcn_perm)
    // D = [ua.b2, ua.b3, ub.b2, ub.b3] -> lo16 = a>>16, hi16 = b>>16
    return __builtin_amdgcn_perm(ub, ua, 0x07060302u);
#else
    return (ua >> 16) | (ub & 0xFFFF0000u);
#endif
}

static __device__ __forceinline__ float fast_exp2(float x) {
#if __has_builtin(__builtin_amdgcn_exp2f)
    return __builtin_amdgcn_exp2f(x);
#else
    return exp2f(x);
#endif
}

static __device__ __forceinline__ bf16x8 ld_frag(const ushort* p) {
    return *(const bf16x8*)p;
}

static __device__ __forceinline__ bf16x8 mk_frag(unsigned int a, unsigned int b,
                                                 unsigned int c, unsigned int d) {
    union { unsigned int u[4]; bf16x8 v; } t;
    t.u[0] = a; t.u[1] = b; t.u[2] = c; t.u[3] = d;
    return t.v;
}

// ---------------------------------------------------------------------------
// D0: dtype detect (bf16 -> 0, fp32 -> 1) from exponent-field sanity.
// ---------------------------------------------------------------------------
__global__ __launch_bounds__(256) void detect_kernel(const ushort* __restrict__ x,
                                                     int* __restrict__ flag) {
    __shared__ int cnt[256];
    const int tid = threadIdx.x;
    int c = 0;
    for (int j = 0; j < 16; ++j) {
        unsigned short w = x[tid * 16 + j];
        int e = (w >> 7) & 0xFF;
        bool sane = (e == 0) || (e >= 0x60 && e <= 0x8F);
        c += sane ? 0 : 1;
    }
    cnt[tid] = c;
    __syncthreads();
    for (int s = 128; s > 0; s >>= 1) {
        if (tid < s) cnt[tid] += cnt[tid + s];
        __syncthreads();
    }
    if (tid == 0) flag[0] = (cnt[0] > 256) ? 1 : 0;
}

// ---------------------------------------------------------------------------
// D1: convert + permute row-major [R][1024] into frag16 layout:
// idx = ((m/16)*32 + k/32)*512 + ((k/8)%4)*128 + (m%16)*8 + k%8
// ---------------------------------------------------------------------------
__global__ __launch_bounds__(256) void convert_frag_kernel(
    const void* __restrict__ src, ushort* __restrict__ dst, int R,
    const int* __restrict__ flag)
{
    const int t = blockIdx.x * 256 + threadIdx.x;
    if (t >= R * 128) return;
    const int m = t >> 7, kc = t & 127;

    u16x8 v;
    if (flag[0]) {
        const float* s = (const float*)src + (size_t)t * 8;
        #pragma unroll
        for (int j = 0; j < 8; ++j) v[j] = f2bf(s[j]);
    } else {
        v = *((const u16x8*)src + t);
    }
    const size_t o = (((size_t)(m >> 4) * 32 + (kc >> 2)) * 64 + (kc & 3) * 16 + (m & 15)) * 8;
    *(u16x8*)(dst + o) = v;
}

// ---------------------------------------------------------------------------
// K1: qkv = x @ w_qkv^T from frag16 XF/WQKVF; epilogue scatters into
// attn-fragment-ready QF/KF/VF. Block = 4 waves, 128x128 tile (64x64 each).
// ---------------------------------------------------------------------------
__global__ __launch_bounds__(256) void qkv_gemm_kernel(
    const ushort* __restrict__ XF, const ushort* __restrict__ WF,
    ushort* __restrict__ QF, ushort* __restrict__ KF, ushort* __restrict__ VF)
{
    const int lane = threadIdx.x & 63;
    const int wave = threadIdx.x >> 6;
    const int col  = lane & 15;
    const int quad = lane >> 4;
    const int m0 = blockIdx.y * 128 + (wave >> 1) * 64;
    const int e0 = blockIdx.x * 128 + (wave & 1) * 64;
    const int mt0 = m0 >> 4, et0 = e0 >> 4;

    f32x4 acc[4][4];
    #pragma unroll
    for (int i = 0; i < 4; ++i)
        #pragma unroll
        for (int j = 0; j < 4; ++j) acc[i][j] = f32x4{0.f, 0.f, 0.f, 0.f};

    for (int kt = 0; kt < 32; ++kt) {
        bf16x8 a[4], b[4];
        #pragma unroll
        for (int i = 0; i < 4; ++i) {
            a[i] = ld_frag(XF + ((size_t)((mt0 + i) * 32 + kt) * 64 + lane) * 8);
            b[i] = ld_frag(WF + ((size_t)((et0 + i) * 32 + kt) * 64 + lane) * 8);
        }
        #pragma unroll
        for (int i = 0; i < 4; ++i)
            #pragma unroll
            for (int j = 0; j < 4; ++j)
                acc[i][j] = __builtin_amdgcn_mfma_f32_16x16x32_bf16(a[i], b[j], acc[i][j], 0, 0, 0);
    }

    #pragma unroll
    for (int ej = 0; ej < 4; ++ej) {
        const int e = e0 + ej * 16 + col;
        const int h = e / 192;
        const int c = e - h * 192;     // 0..63 q | 64..127 k | 128..191 v
        #pragma unroll
        for (int mi = 0; mi < 4; ++mi) {
            #pragma unroll
            for (int r = 0; r < 4; ++r) {
                const int m = m0 + mi * 16 + quad * 4 + r;
                const int bh = (m >> 11) * NH + h;
                const int n = m & (SEQ - 1);
                const float val = acc[mi][ej][r];
                if (c < 64) {
                    const int d = c;
                    QF[(((size_t)(bh * 64 + (n >> 5)) * 4 + (d >> 4)) * 64
                        + ((d >> 3) & 1) * 32 + (n & 31)) * 8 + (d & 7)] = f2bf_fast(val * QSCALE);
                } else if (c < 128) {
                    const int d = c - 64;
                    KF[(((size_t)(bh * 64 + (n >> 5)) * 4 + (d >> 4)) * 64
                        + ((d >> 3) & 1) * 32 + (n & 31)) * 8 + (d & 7)] = f2bf_fast(val);
                } else {
                    const int d = c - 128;
                    VF[((((size_t)(bh * 32 + (n >> 6)) * 2 + (d >> 5)) * 4 + ((n >> 4) & 3)) * 64
                        + ((n >> 3) & 1) * 32 + (d & 31)) * 8 + (n & 7)] = f2bf_fast(val);
                }
            }
        }
    }
}

// ---------------------------------------------------------------------------
// K2: flash attention, S^T formulation, max-free exp2 softmax.
// KV-SPLIT: block = 4 waves = 2 q-tiles x 2 kv-halves of one (b,h); partial
// (O_unnorm, l) sums combine exactly via one LDS round-trip. grid = 2048.
// XCD-swizzled: 32 blocks/bh on one XCD (K+V 512KB/bh, 8 bh/XCD L2-resident).
// VALU diet: v_perm bf16 packs, unroll-2 for cross-iteration load hoisting.
// ---------------------------------------------------------------------------
__global__ __launch_bounds__(256) void attn_kernel(
    const ushort* __restrict__ QF, const ushort* __restrict__ KF,
    const ushort* __restrict__ VF, ushort* __restrict__ AOF)
{
    __shared__ float lred[2][33][64];   // [qt][acc0 16 | acc1 16 | l][lane]

    const int lane = threadIdx.x & 63;
    const int wave = threadIdx.x >> 6;
    const int half = lane >> 5;
    const int l31  = lane & 31;

    const int i = blockIdx.x;
    const int xcd = i & 7;
    const int s = i >> 3;
    const int qc = s & 31;                     // 64-q chunk within bh
    const int bh = ((s >> 5) << 3) | xcd;      // [0,64)
    const int qt  = wave & 1;                  // q-tile within chunk
    const int kvh = wave >> 1;                 // kv half
    const int q0 = qc * 64 + qt * 32;

    // Q^T B-fragments (coalesced)
    const ushort* qfb = QF + ((size_t)(bh * 64 + (q0 >> 5)) * 4) * 512;
    bf16x8 bq[4];
    #pragma unroll
    for (int d4 = 0; d4 < 4; ++d4) bq[d4] = ld_frag(qfb + d4 * 512 + lane * 8);

    const ushort* kfb = KF + (size_t)bh * 131072 + (size_t)kvh * 65536;
    const ushort* vfb = VF + (size_t)bh * 131072 + (size_t)kvh * 65536;

    float l_i = 0.f;
    f32x16 acc0 = {}, acc1 = {};   // O^T d-tiles 0..31 / 32..63 (unnormalized)

    #pragma unroll 2
    for (int it = 0; it < 16; ++it) {
        // V^T A-fragments (independent; overlaps softmax)
        const ushort* vp = vfb + (size_t)it * 4096;
        bf16x8 va0[4], va1[4];
        #pragma unroll
        for (int f4 = 0; f4 < 4; ++f4) {
            va0[f4] = ld_frag(vp + f4 * 512 + lane * 8);
            va1[f4] = ld_frag(vp + (4 + f4) * 512 + lane * 8);
        }

        // S^T = K·Q^T
        f32x16 st0 = {}, st1 = {};
        const ushort* kp = kfb + (size_t)it * 4096;
        #pragma unroll
        for (int d4 = 0; d4 < 4; ++d4) {
            bf16x8 ka0 = ld_frag(kp + d4 * 512 + lane * 8);
            bf16x8 ka1 = ld_frag(kp + (4 + d4) * 512 + lane * 8);
            st0 = __builtin_amdgcn_mfma_f32_32x32x16_bf16(ka0, bq[d4], st0, 0, 0, 0);
            st1 = __builtin_amdgcn_mfma_f32_32x32x16_bf16(ka1, bq[d4], st1, 0, 0, 0);
        }

        // max-free softmax: p = exp2(st); l = plain running sum
        float rs = 0.f;
        #pragma unroll
        for (int t = 0; t < 16; ++t) { st0[t] = fast_exp2(st0[t]); rs += st0[t]; }
        #pragma unroll
        for (int t = 0; t < 16; ++t) { st1[t] = fast_exp2(st1[t]); rs += st1[t]; }
        l_i += rs;

        // P^T -> B-fragments: v_perm pack, half-wave row exchange
        unsigned int u[16], ex[16];
        #pragma unroll
        for (int t = 0; t < 8; ++t) u[t]     = pkbf_fast(st0[2 * t], st0[2 * t + 1]);
        #pragma unroll
        for (int t = 0; t < 8; ++t) u[8 + t] = pkbf_fast(st1[2 * t], st1[2 * t + 1]);
        #pragma unroll
        for (int t = 0; t < 16; ++t) ex[t] = __shfl_xor(u[t], 32, 64);

        bf16x8 pf[4];
        pf[0] = half == 0 ? mk_frag(u[0], u[1], ex[0], ex[1])     : mk_frag(ex[2], ex[3], u[2], u[3]);
        pf[1] = half == 0 ? mk_frag(u[4], u[5], ex[4], ex[5])     : mk_frag(ex[6], ex[7], u[6], u[7]);
        pf[2] = half == 0 ? mk_frag(u[8], u[9], ex[8], ex[9])     : mk_frag(ex[10], ex[11], u[10], u[11]);
        pf[3] = half == 0 ? mk_frag(u[12], u[13], ex[12], ex[13]) : mk_frag(ex[14], ex[15], u[14], u[15]);

        // O^T += V^T · P^T
        #pragma unroll
        for (int f4 = 0; f4 < 4; ++f4) {
            acc0 = __builtin_amdgcn_mfma_f32_32x32x16_bf16(va0[f4], pf[f4], acc0, 0, 0, 0);
            acc1 = __builtin_amdgcn_mfma_f32_32x32x16_bf16(va1[f4], pf[f4], acc1, 0, 0, 0);
        }
    }

    // each wave: combine l across lane-halves (both halves hold same q cols)
    l_i += __shfl_xor(l_i, 32, 64);

    // kv-half combine via LDS (additive; exact for max-free softmax)
    if (kvh == 1) {
        #pragma unroll
        for (int r = 0; r < 16; ++r) {
            lred[qt][r][lane]      = acc0[r];
            lred[qt][16 + r][lane] = acc1[r];
        }
        lred[qt][32][lane] = l_i;
    }
    __syncthreads();
    if (kvh == 0) {
        #pragma unroll
        for (int r = 0; r < 16; ++r) {
            acc0[r] += lred[qt][r][lane];
            acc1[r] += lred[qt][16 + r][lane];
        }
        l_i += lred[qt][32][lane];

        const int b = bh >> 4, h = bh & (NH - 1);
        const float inv = 1.f / l_i;
        const int n_g = b * SEQ + q0 + l31;
        #pragma unroll
        for (int r = 0; r < 16; ++r) {
            const int d = (r & 3) + 8 * (r >> 2) + 4 * half;
            #pragma unroll
            for (int p = 0; p < 2; ++p) {
                const int e = h * 64 + p * 32 + d;
                const float val = (p == 0 ? acc0[r] : acc1[r]) * inv;
                AOF[(((size_t)(n_g >> 4) * 32 + (e >> 5)) * 64
                     + ((e >> 3) & 3) * 16 + (n_g & 15)) * 8 + (e & 7)] = f2bf_fast(val);
            }
        }
    }
}

// ---------------------------------------------------------------------------
// K3: out = AO @ w_o^T from frag16 AOF/WOF. Block = 4 waves, 128x128 tile.
// Output row-major, dtype by flag. grid = (DM/128, M_TOT/128)
// ---------------------------------------------------------------------------
__global__ __launch_bounds__(256) void out_gemm_kernel(
    const ushort* __restrict__ AOF, const ushort* __restrict__ WOF,
    void* __restrict__ out, const int* __restrict__ flag)
{
    const int lane = threadIdx.x & 63;
    const int wave = threadIdx.x >> 6;
    const int col  = lane & 15;
    const int quad = lane >> 4;
    const int m0 = blockIdx.y * 128 + (wave >> 1) * 64;
    const int e0 = blockIdx.x * 128 + (wave & 1) * 64;
    const int mt0 = m0 >> 4, et0 = e0 >> 4;
    const int f = flag[0];

    f32x4 acc[4][4];
    #pragma unroll
    for (int i = 0; i < 4; ++i)
        #pragma unroll
        for (int j = 0; j < 4; ++j) acc[i][j] = f32x4{0.f, 0.f, 0.f, 0.f};

    for (int kt = 0; kt < 32; ++kt) {
        bf16x8 a[4], b[4];
        #pragma unroll
        for (int i = 0; i < 4; ++i) {
            a[i] = ld_frag(AOF + ((size_t)((mt0 + i) * 32 + kt) * 64 + lane) * 8);
            b[i] = ld_frag(WOF + ((size_t)((et0 + i) * 32 + kt) * 64 + lane) * 8);
        }
        #pragma unroll
        for (int i = 0; i < 4; ++i)
            #pragma unroll
            for (int j = 0; j < 4; ++j)
                acc[i][j] = __builtin_amdgcn_mfma_f32_16x16x32_bf16(a[i], b[j], acc[i][j], 0, 0, 0);
    }

    if (f == 0) {
        ushort* o = (ushort*)out;
        #pragma unroll
        for (int mi = 0; mi < 4; ++mi)
            #pragma unroll
            for (int ej = 0; ej < 4; ++ej)
                #pragma unroll
                for (int r = 0; r < 4; ++r)
                    o[(size_t)(m0 + mi * 16 + quad * 4 + r) * DM + e0 + ej * 16 + col] = f2bf_fast(acc[mi][ej][r]);
    } else {
        float* o = (float*)out;
        #pragma unroll
        for (int mi = 0; mi < 4; ++mi)
            #pragma unroll
            for (int ej = 0; ej < 4; ++ej)
                #pragma unroll
                for (int r = 0; r < 4; ++r)
                    o[(size_t)(m0 + mi * 16 + quad * 4 + r) * DM + e0 + ej * 16 + col] = acc[mi][ej][r];
    }
}

// ---------------------------------------------------------------------------
extern "C" void kernel_launch(void* const* d_in, const int* in_sizes, int n_in,
                              void* d_out, int out_size, void* d_ws, size_t ws_size,
                              hipStream_t stream) {
    const void* x_raw     = d_in[0];
    const void* w_qkv_raw = d_in[1];
    const void* w_o_raw   = d_in[2];

    // ws: flag(256B) | XF(16MiB, reused as AOF) | WQKVF(6MiB) | WOF(2MiB)
    //     | QF(16MiB) | KF(16MiB) | VF(16MiB)   = 72 MiB + 256 B
    char* ws = (char*)d_ws;
    int*    flag  = (int*)ws;
    ushort* XF    = (ushort*)(ws + 256);
    ushort* WQKVF = (ushort*)(ws + 256 + (16u << 20));
    ushort* WOF   = (ushort*)(ws + 256 + (22u << 20));
    ushort* QF    = (ushort*)(ws + 256 + (24u << 20));
    ushort* KF    = (ushort*)(ws + 256 + (40u << 20));
    ushort* VF    = (ushort*)(ws + 256 + (56u << 20));
    ushort* AOF   = XF;   // XF dead after K1

    detect_kernel<<<1, 256, 0, stream>>>((const ushort*)x_raw, flag);
    convert_frag_kernel<<<M_TOT / 2, 256, 0, stream>>>(x_raw, XF, M_TOT, flag);
    convert_frag_kernel<<<EQKV / 2, 256, 0, stream>>>(w_qkv_raw, WQKVF, EQKV, flag);
    convert_frag_kernel<<<DM / 2, 256, 0, stream>>>(w_o_raw, WOF, DM, flag);

    qkv_gemm_kernel<<<dim3(EQKV / 128, M_TOT / 128), 256, 0, stream>>>(XF, WQKVF, QF, KF, VF);
    attn_kernel<<<dim3(BATCH * NH * (SEQ / 64)), 256, 0, stream>>>(QF, KF, VF, AOF);
    out_gemm_kernel<<<dim3(DM / 128, M_TOT / 128), 256, 0, stream>>>(AOF, WOF, d_out, flag);
}

// Round 9
// 304.289 us; speedup vs baseline: 1.0713x; 1.0713x over previous
//
#include <hip/hip_runtime.h>

// MultiHeadSelfAttention: x[4,2048,1024], w_qkv[3072,1024], w_o[1024,1024]
// Inputs fp32 (runtime-detected); all compute bf16 MFMA; every intermediate
// stored FRAGMENT-READY so every MFMA operand load is base + lane*16B.
// V is additionally sigma-PERMUTED in kv so the PV B-fragment is built from
// the S^T C-layout registers directly (no cross-lane exchange).
#define BATCH 4
#define SEQ 2048
#define DM 1024
#define NH 16
#define DH 64
#define M_TOT (BATCH * SEQ)   // 8192
#define EQKV (3 * DM)         // 3072
// 0.125 (1/sqrt(dh)) * log2(e): folded into Q; softmax in exp2 domain
#define QSCALE 0.18033688011112042f

typedef __bf16 bf16x8 __attribute__((ext_vector_type(8)));
typedef unsigned short u16x8 __attribute__((ext_vector_type(8)));
typedef float f32x4 __attribute__((ext_vector_type(4)));
typedef float f32x16 __attribute__((ext_vector_type(16)));

// RNE fp32->bf16 (used only in input canonicalization)
static __device__ __forceinline__ unsigned short f2bf(float f) {
    unsigned int u = __builtin_bit_cast(unsigned int, f);
    u += 0x7fffu + ((u >> 16) & 1u);
    return (unsigned short)(u >> 16);
}

// fast fp32->bf16, round-half-up (2 VALU): bias +2^-17 relative, negligible
static __device__ __forceinline__ unsigned short f2bf_fast(float f) {
    return (unsigned short)((__builtin_bit_cast(unsigned int, f) + 0x8000u) >> 16);
}

// fast pack two fp32 -> bf16 pair (3 VALU: 2 adds + 1 v_perm_b32)
static __device__ __forceinline__ unsigned int pkbf_fast(float a, float b) {
    unsigned int ua = __builtin_bit_cast(unsigned int, a) + 0x8000u;
    unsigned int ub = __builtin_bit_cast(unsigned int, b) + 0x8000u;
#if __has_builtin(__builtin_amdgcn_perm)
    // D = [ua.b2, ua.b3, ub.b2, ub.b3] -> lo16 = a>>16, hi16 = b>>16
    return __builtin_amdgcn_perm(ub, ua, 0x07060302u);
#else
    return (ua >> 16) | (ub & 0xFFFF0000u);
#endif
}

static __device__ __forceinline__ float fast_exp2(float x) {
#if __has_builtin(__builtin_amdgcn_exp2f)
    return __builtin_amdgcn_exp2f(x);
#else
    return exp2f(x);
#endif
}

static __device__ __forceinline__ bf16x8 ld_frag(const ushort* p) {
    return *(const bf16x8*)p;
}

static __device__ __forceinline__ bf16x8 mk_frag(unsigned int a, unsigned int b,
                                                 unsigned int c, unsigned int d) {
    union { unsigned int u[4]; bf16x8 v; } t;
    t.u[0] = a; t.u[1] = b; t.u[2] = c; t.u[3] = d;
    return t.v;
}

// ---------------------------------------------------------------------------
// D0: dtype detect (bf16 -> 0, fp32 -> 1) from exponent-field sanity.
// ---------------------------------------------------------------------------
__global__ __launch_bounds__(256) void detect_kernel(const ushort* __restrict__ x,
                                                     int* __restrict__ flag) {
    __shared__ int cnt[256];
    const int tid = threadIdx.x;
    int c = 0;
    for (int j = 0; j < 16; ++j) {
        unsigned short w = x[tid * 16 + j];
        int e = (w >> 7) & 0xFF;
        bool sane = (e == 0) || (e >= 0x60 && e <= 0x8F);
        c += sane ? 0 : 1;
    }
    cnt[tid] = c;
    __syncthreads();
    for (int s = 128; s > 0; s >>= 1) {
        if (tid < s) cnt[tid] += cnt[tid + s];
        __syncthreads();
    }
    if (tid == 0) flag[0] = (cnt[0] > 256) ? 1 : 0;
}

// ---------------------------------------------------------------------------
// D1: convert + permute row-major [R][1024] into frag16 layout:
// idx = ((m/16)*32 + k/32)*512 + ((k/8)%4)*128 + (m%16)*8 + k%8
// ---------------------------------------------------------------------------
__global__ __launch_bounds__(256) void convert_frag_kernel(
    const void* __restrict__ src, ushort* __restrict__ dst, int R,
    const int* __restrict__ flag)
{
    const int t = blockIdx.x * 256 + threadIdx.x;
    if (t >= R * 128) return;
    const int m = t >> 7, kc = t & 127;

    u16x8 v;
    if (flag[0]) {
        const float* s = (const float*)src + (size_t)t * 8;
        #pragma unroll
        for (int j = 0; j < 8; ++j) v[j] = f2bf(s[j]);
    } else {
        v = *((const u16x8*)src + t);
    }
    const size_t o = (((size_t)(m >> 4) * 32 + (kc >> 2)) * 64 + (kc & 3) * 16 + (m & 15)) * 8;
    *(u16x8*)(dst + o) = v;
}

// ---------------------------------------------------------------------------
// K1: qkv = x @ w_qkv^T from frag16 XF/WQKVF; epilogue scatters into
// attn-fragment-ready QF/KF/VF (VF sigma-permuted in kv).
// Block = 4 waves, 128x128 tile (64x64 each).
// ---------------------------------------------------------------------------
__global__ __launch_bounds__(256) void qkv_gemm_kernel(
    const ushort* __restrict__ XF, const ushort* __restrict__ WF,
    ushort* __restrict__ QF, ushort* __restrict__ KF, ushort* __restrict__ VF)
{
    const int lane = threadIdx.x & 63;
    const int wave = threadIdx.x >> 6;
    const int col  = lane & 15;
    const int quad = lane >> 4;
    const int m0 = blockIdx.y * 128 + (wave >> 1) * 64;
    const int e0 = blockIdx.x * 128 + (wave & 1) * 64;
    const int mt0 = m0 >> 4, et0 = e0 >> 4;

    f32x4 acc[4][4];
    #pragma unroll
    for (int i = 0; i < 4; ++i)
        #pragma unroll
        for (int j = 0; j < 4; ++j) acc[i][j] = f32x4{0.f, 0.f, 0.f, 0.f};

    for (int kt = 0; kt < 32; ++kt) {
        bf16x8 a[4], b[4];
        #pragma unroll
        for (int i = 0; i < 4; ++i) {
            a[i] = ld_frag(XF + ((size_t)((mt0 + i) * 32 + kt) * 64 + lane) * 8);
            b[i] = ld_frag(WF + ((size_t)((et0 + i) * 32 + kt) * 64 + lane) * 8);
        }
        #pragma unroll
        for (int i = 0; i < 4; ++i)
            #pragma unroll
            for (int j = 0; j < 4; ++j)
                acc[i][j] = __builtin_amdgcn_mfma_f32_16x16x32_bf16(a[i], b[j], acc[i][j], 0, 0, 0);
    }

    #pragma unroll
    for (int ej = 0; ej < 4; ++ej) {
        const int e = e0 + ej * 16 + col;
        const int h = e / 192;
        const int c = e - h * 192;     // 0..63 q | 64..127 k | 128..191 v
        #pragma unroll
        for (int mi = 0; mi < 4; ++mi) {
            #pragma unroll
            for (int r = 0; r < 4; ++r) {
                const int m = m0 + mi * 16 + quad * 4 + r;
                const int bh = (m >> 11) * NH + h;
                const int n = m & (SEQ - 1);
                const float val = acc[mi][ej][r];
                if (c < 64) {
                    const int d = c;
                    QF[(((size_t)(bh * 64 + (n >> 5)) * 4 + (d >> 4)) * 64
                        + ((d >> 3) & 1) * 32 + (n & 31)) * 8 + (d & 7)] = f2bf_fast(val * QSCALE);
                } else if (c < 128) {
                    const int d = c - 64;
                    KF[(((size_t)(bh * 64 + (n >> 5)) * 4 + (d >> 4)) * 64
                        + ((d >> 3) & 1) * 32 + (n & 31)) * 8 + (d & 7)] = f2bf_fast(val);
                } else {
                    const int d = c - 128;
                    // sigma slot: B-frag of PV is S^T C-layout regs in order
                    const int r4 = n & 15;
                    const int s4 = (r4 & 3) | (((r4 >> 3) & 1) << 2) | (((r4 >> 2) & 1) << 3);
                    VF[((((size_t)(bh * 32 + (n >> 6)) * 2 + (d >> 5)) * 4 + ((n >> 4) & 3)) * 64
                        + (s4 >> 3) * 32 + (d & 31)) * 8 + (s4 & 7)] = f2bf_fast(val);
                }
            }
        }
    }
}

// ---------------------------------------------------------------------------
// K2: flash attention, S^T formulation, max-free exp2 softmax, NO cross-lane
// exchange: sigma-permuted VF makes the PV B-fragment = packed S^T C-regs
// (k-tile 0 = regs 0..7, k-tile 1 = regs 8..15, uniform across halves).
// KV-SPLIT: block = 4 waves = 2 q-tiles x 2 kv-halves of one (b,h); partial
// (O_unnorm, l) sums combine exactly via one LDS round-trip. grid = 2048.
// XCD-swizzled: 32 blocks/bh on one XCD.
// ---------------------------------------------------------------------------
__global__ __launch_bounds__(256) void attn_kernel(
    const ushort* __restrict__ QF, const ushort* __restrict__ KF,
    const ushort* __restrict__ VF, ushort* __restrict__ AOF)
{
    __shared__ float lred[2][33][64];   // [qt][acc0 16 | acc1 16 | l][lane]

    const int lane = threadIdx.x & 63;
    const int wave = threadIdx.x >> 6;
    const int half = lane >> 5;
    const int l31  = lane & 31;

    const int i = blockIdx.x;
    const int xcd = i & 7;
    const int s = i >> 3;
    const int qc = s & 31;                     // 64-q chunk within bh
    const int bh = ((s >> 5) << 3) | xcd;      // [0,64)
    const int qt  = wave & 1;                  // q-tile within chunk
    const int kvh = wave >> 1;                 // kv half
    const int q0 = qc * 64 + qt * 32;

    // Q^T B-fragments (coalesced)
    const ushort* qfb = QF + ((size_t)(bh * 64 + (q0 >> 5)) * 4) * 512;
    bf16x8 bq[4];
    #pragma unroll
    for (int d4 = 0; d4 < 4; ++d4) bq[d4] = ld_frag(qfb + d4 * 512 + lane * 8);

    const ushort* kfb = KF + (size_t)bh * 131072 + (size_t)kvh * 65536;
    const ushort* vfb = VF + (size_t)bh * 131072 + (size_t)kvh * 65536;

    float l_i = 0.f;
    f32x16 acc0 = {}, acc1 = {};   // O^T d-tiles 0..31 / 32..63 (unnormalized)

    for (int it = 0; it < 16; ++it) {
        // V^T A-fragments (independent; overlaps softmax)
        const ushort* vp = vfb + (size_t)it * 4096;
        bf16x8 va0[4], va1[4];
        #pragma unroll
        for (int f4 = 0; f4 < 4; ++f4) {
            va0[f4] = ld_frag(vp + f4 * 512 + lane * 8);
            va1[f4] = ld_frag(vp + (4 + f4) * 512 + lane * 8);
        }

        // S^T = K·Q^T
        f32x16 st0 = {}, st1 = {};
        const ushort* kp = kfb + (size_t)it * 4096;
        #pragma unroll
        for (int d4 = 0; d4 < 4; ++d4) {
            bf16x8 ka0 = ld_frag(kp + d4 * 512 + lane * 8);
            bf16x8 ka1 = ld_frag(kp + (4 + d4) * 512 + lane * 8);
            st0 = __builtin_amdgcn_mfma_f32_32x32x16_bf16(ka0, bq[d4], st0, 0, 0, 0);
            st1 = __builtin_amdgcn_mfma_f32_32x32x16_bf16(ka1, bq[d4], st1, 0, 0, 0);
        }

        // max-free softmax: p = exp2(st); l = plain running sum
        float rs = 0.f;
        #pragma unroll
        for (int t = 0; t < 16; ++t) { st0[t] = fast_exp2(st0[t]); rs += st0[t]; }
        #pragma unroll
        for (int t = 0; t < 16; ++t) { st1[t] = fast_exp2(st1[t]); rs += st1[t]; }
        l_i += rs;

        // P^T B-fragments directly from C-layout regs (sigma-permuted V)
        bf16x8 pf[4];
        pf[0] = mk_frag(pkbf_fast(st0[0],  st0[1]),  pkbf_fast(st0[2],  st0[3]),
                        pkbf_fast(st0[4],  st0[5]),  pkbf_fast(st0[6],  st0[7]));
        pf[1] = mk_frag(pkbf_fast(st0[8],  st0[9]),  pkbf_fast(st0[10], st0[11]),
                        pkbf_fast(st0[12], st0[13]), pkbf_fast(st0[14], st0[15]));
        pf[2] = mk_frag(pkbf_fast(st1[0],  st1[1]),  pkbf_fast(st1[2],  st1[3]),
                        pkbf_fast(st1[4],  st1[5]),  pkbf_fast(st1[6],  st1[7]));
        pf[3] = mk_frag(pkbf_fast(st1[8],  st1[9]),  pkbf_fast(st1[10], st1[11]),
                        pkbf_fast(st1[12], st1[13]), pkbf_fast(st1[14], st1[15]));

        // O^T += V^T · P^T
        #pragma unroll
        for (int f4 = 0; f4 < 4; ++f4) {
            acc0 = __builtin_amdgcn_mfma_f32_32x32x16_bf16(va0[f4], pf[f4], acc0, 0, 0, 0);
            acc1 = __builtin_amdgcn_mfma_f32_32x32x16_bf16(va1[f4], pf[f4], acc1, 0, 0, 0);
        }
    }

    // combine l across lane-halves (both halves hold the same q columns)
    l_i += __shfl_xor(l_i, 32, 64);

    // kv-half combine via LDS (additive; exact for max-free softmax)
    if (kvh == 1) {
        #pragma unroll
        for (int r = 0; r < 16; ++r) {
            lred[qt][r][lane]      = acc0[r];
            lred[qt][16 + r][lane] = acc1[r];
        }
        lred[qt][32][lane] = l_i;
    }
    __syncthreads();
    if (kvh == 0) {
        #pragma unroll
        for (int r = 0; r < 16; ++r) {
            acc0[r] += lred[qt][r][lane];
            acc1[r] += lred[qt][16 + r][lane];
        }
        l_i += lred[qt][32][lane];

        const int b = bh >> 4, h = bh & (NH - 1);
        const float inv = 1.f / l_i;
        const int n_g = b * SEQ + q0 + l31;
        #pragma unroll
        for (int r = 0; r < 16; ++r) {
            const int d = (r & 3) + 8 * (r >> 2) + 4 * half;
            #pragma unroll
            for (int p = 0; p < 2; ++p) {
                const int e = h * 64 + p * 32 + d;
                const float val = (p == 0 ? acc0[r] : acc1[r]) * inv;
                AOF[(((size_t)(n_g >> 4) * 32 + (e >> 5)) * 64
                     + ((e >> 3) & 3) * 16 + (n_g & 15)) * 8 + (e & 7)] = f2bf_fast(val);
            }
        }
    }
}

// ---------------------------------------------------------------------------
// K3: out = AO @ w_o^T from frag16 AOF/WOF. Block = 4 waves, 128x128 tile.
// Output row-major, dtype by flag. grid = (DM/128, M_TOT/128)
// ---------------------------------------------------------------------------
__global__ __launch_bounds__(256) void out_gemm_kernel(
    const ushort* __restrict__ AOF, const ushort* __restrict__ WOF,
    void* __restrict__ out, const int* __restrict__ flag)
{
    const int lane = threadIdx.x & 63;
    const int wave = threadIdx.x >> 6;
    const int col  = lane & 15;
    const int quad = lane >> 4;
    const int m0 = blockIdx.y * 128 + (wave >> 1) * 64;
    const int e0 = blockIdx.x * 128 + (wave & 1) * 64;
    const int mt0 = m0 >> 4, et0 = e0 >> 4;
    const int f = flag[0];

    f32x4 acc[4][4];
    #pragma unroll
    for (int i = 0; i < 4; ++i)
        #pragma unroll
        for (int j = 0; j < 4; ++j) acc[i][j] = f32x4{0.f, 0.f, 0.f, 0.f};

    for (int kt = 0; kt < 32; ++kt) {
        bf16x8 a[4], b[4];
        #pragma unroll
        for (int i = 0; i < 4; ++i) {
            a[i] = ld_frag(AOF + ((size_t)((mt0 + i) * 32 + kt) * 64 + lane) * 8);
            b[i] = ld_frag(WOF + ((size_t)((et0 + i) * 32 + kt) * 64 + lane) * 8);
        }
        #pragma unroll
        for (int i = 0; i < 4; ++i)
            #pragma unroll
            for (int j = 0; j < 4; ++j)
                acc[i][j] = __builtin_amdgcn_mfma_f32_16x16x32_bf16(a[i], b[j], acc[i][j], 0, 0, 0);
    }

    if (f == 0) {
        ushort* o = (ushort*)out;
        #pragma unroll
        for (int mi = 0; mi < 4; ++mi)
            #pragma unroll
            for (int ej = 0; ej < 4; ++ej)
                #pragma unroll
                for (int r = 0; r < 4; ++r)
                    o[(size_t)(m0 + mi * 16 + quad * 4 + r) * DM + e0 + ej * 16 + col] = f2bf_fast(acc[mi][ej][r]);
    } else {
        float* o = (float*)out;
        #pragma unroll
        for (int mi = 0; mi < 4; ++mi)
            #pragma unroll
            for (int ej = 0; ej < 4; ++ej)
                #pragma unroll
                for (int r = 0; r < 4; ++r)
                    o[(size_t)(m0 + mi * 16 + quad * 4 + r) * DM + e0 + ej * 16 + col] = acc[mi][ej][r];
    }
}

// ---------------------------------------------------------------------------
extern "C" void kernel_launch(void* const* d_in, const int* in_sizes, int n_in,
                              void* d_out, int out_size, void* d_ws, size_t ws_size,
                              hipStream_t stream) {
    const void* x_raw     = d_in[0];
    const void* w_qkv_raw = d_in[1];
    const void* w_o_raw   = d_in[2];

    // ws: flag(256B) | XF(16MiB, reused as AOF) | WQKVF(6MiB) | WOF(2MiB)
    //     | QF(16MiB) | KF(16MiB) | VF(16MiB)   = 72 MiB + 256 B
    char* ws = (char*)d_ws;
    int*    flag  = (int*)ws;
    ushort* XF    = (ushort*)(ws + 256);
    ushort* WQKVF = (ushort*)(ws + 256 + (16u << 20));
    ushort* WOF   = (ushort*)(ws + 256 + (22u << 20));
    ushort* QF    = (ushort*)(ws + 256 + (24u << 20));
    ushort* KF    = (ushort*)(ws + 256 + (40u << 20));
    ushort* VF    = (ushort*)(ws + 256 + (56u << 20));
    ushort* AOF   = XF;   // XF dead after K1

    detect_kernel<<<1, 256, 0, stream>>>((const ushort*)x_raw, flag);
    convert_frag_kernel<<<M_TOT / 2, 256, 0, stream>>>(x_raw, XF, M_TOT, flag);
    convert_frag_kernel<<<EQKV / 2, 256, 0, stream>>>(w_qkv_raw, WQKVF, EQKV, flag);
    convert_frag_kernel<<<DM / 2, 256, 0, stream>>>(w_o_raw, WOF, DM, flag);

    qkv_gemm_kernel<<<dim3(EQKV / 128, M_TOT / 128), 256, 0, stream>>>(XF, WQKVF, QF, KF, VF);
    attn_kernel<<<dim3(BATCH * NH * (SEQ / 64)), 256, 0, stream>>>(QF, KF, VF, AOF);
    out_gemm_kernel<<<dim3(DM / 128, M_TOT / 128), 256, 0, stream>>>(AOF, WOF, d_out, flag);
}